// Round 1
// baseline (523.066 us; speedup 1.0000x reference)
//
#include <hip/hip_runtime.h>
#include <hip/hip_bf16.h>

// Problem constants
#define B_   128
#define N_   68
#define C_   3
#define P_   32
#define K_   16
#define FD_  64
#define GH_  128
#define EG_  544          // 8*N
#define T_   8704         // B*N
#define FLAT_ 4096        // K*16*16

// ---------------------------------------------------------------------------
// K1: per-node conv3x3(SAME) + bias + relu + maxpool2x2 -> pooled[T][4096]
// One block per node (8704 blocks, 256 threads). x staged in zero-padded LDS.
// Thread = (py,px) pooled position, computes all 16 kernels (x window in regs,
// weights via SGPR uniform loads).
// ---------------------------------------------------------------------------
__global__ __launch_bounds__(256) void conv_pool_kernel(
    const float* __restrict__ x, const float* __restrict__ conv_w,
    const float* __restrict__ conv_b, float* __restrict__ pooled) {
  const int t = blockIdx.x;
  const int n = t % N_;
  const int tid = threadIdx.x;

  __shared__ float xs[3 * 34 * 34];   // zero-padded [c][34][34]

  for (int i = tid; i < 3 * 34 * 34; i += 256) xs[i] = 0.0f;
  __syncthreads();

  // load interior rows as float4 (global coalesced), scatter to LDS
  const float4* xg = (const float4*)(x + (size_t)t * (C_ * P_ * P_));
  #pragma unroll
  for (int j = 0; j < 3; j++) {
    int i4 = tid + j * 256;          // 768 float4 total
    float4 v = xg[i4];
    int f0 = i4 * 4;
    int c = f0 >> 10, rem = f0 & 1023, y = rem >> 5, xc = rem & 31;
    float* dstp = &xs[c * 1156 + (y + 1) * 34 + xc + 1];
    dstp[0] = v.x; dstp[1] = v.y; dstp[2] = v.z; dstp[3] = v.w;
  }
  __syncthreads();

  const int py = tid >> 4, px = tid & 15;

  // 4x4x3 input window into registers
  float xr[3][4][4];
  #pragma unroll
  for (int c = 0; c < 3; c++)
    #pragma unroll
    for (int r = 0; r < 4; r++)
      #pragma unroll
      for (int cc = 0; cc < 4; cc++)
        xr[c][r][cc] = xs[c * 1156 + (2 * py + r) * 34 + (2 * px + cc)];

  const float* wp = conv_w + (size_t)n * (K_ * 27);
  const float* bp = conv_b + (size_t)n * K_;
  float* outp = pooled + (size_t)t * FLAT_ + py * 16 + px;

  #pragma unroll 2
  for (int k = 0; k < K_; k++) {
    const float* wk = wp + k * 27;
    float bk = bp[k];
    float a00 = bk, a01 = bk, a10 = bk, a11 = bk;
    #pragma unroll
    for (int c = 0; c < 3; c++)
      #pragma unroll
      for (int dy = 0; dy < 3; dy++)
        #pragma unroll
        for (int dx = 0; dx < 3; dx++) {
          float w = wk[c * 9 + dy * 3 + dx];   // uniform -> SGPR
          a00 += xr[c][dy][dx]       * w;
          a01 += xr[c][dy][dx + 1]   * w;
          a10 += xr[c][dy + 1][dx]   * w;
          a11 += xr[c][dy + 1][dx + 1] * w;
        }
    float m = fmaxf(fmaxf(a00, a01), fmaxf(a10, a11));
    m = fmaxf(m, 0.0f);              // relu-then-maxpool == maxpool-then-relu
    outp[k * 256] = m;
  }
}

// ---------------------------------------------------------------------------
// K2: per-type linear, f-split x8 with fp32 atomic accumulation into feats.
// Block = (type n, f-chunk of 512). 128 threads, tile 128 rows x 64 outs,
// thread tile 8x8, inner f-quad b128 LDS reads.
// feats[t][64] holds the PRE-bias, PRE-relu sum (K3 finishes it).
// ---------------------------------------------------------------------------
__global__ __launch_bounds__(128) void lin1_kernel(
    const float* __restrict__ pooled, const float* __restrict__ lin1_w,
    float* __restrict__ feats) {
  const int n  = blockIdx.x >> 3;
  const int fc = blockIdx.x & 7;
  const int tid = threadIdx.x;
  const int oc = tid & 7;       // out group: o = oc*8 .. +7
  const int rg = tid >> 3;      // row group: r = rg*8 .. +7

  __shared__ float pS[128 * 36];   // rows x f-tile(32), pitch 36
  __shared__ float wS[32 * 64];    // f-tile x 64 outs

  float acc[8][8];
  #pragma unroll
  for (int a = 0; a < 8; a++)
    #pragma unroll
    for (int b = 0; b < 8; b++) acc[a][b] = 0.0f;

  const int f_base = fc * 512;
  for (int tile = 0; tile < 16; tile++) {
    const int f0 = f_base + tile * 32;
    // stage pooled tile: 1024 float4
    #pragma unroll
    for (int j = 0; j < 8; j++) {
      int i4 = tid + j * 128;
      int r = i4 >> 3, qf = (i4 & 7) * 4;
      float4 v = *(const float4*)&pooled[(size_t)(r * N_ + n) * FLAT_ + f0 + qf];
      *(float4*)&pS[r * 36 + qf] = v;
    }
    // stage w tile: contiguous 2048 floats
    const float4* wg = (const float4*)&lin1_w[(size_t)n * (FLAT_ * FD_) + (size_t)f0 * FD_];
    #pragma unroll
    for (int j = 0; j < 4; j++) ((float4*)wS)[tid + j * 128] = wg[tid + j * 128];
    __syncthreads();

    #pragma unroll
    for (int fq = 0; fq < 8; fq++) {
      float4 pv[8];
      #pragma unroll
      for (int rr = 0; rr < 8; rr++)
        pv[rr] = *(const float4*)&pS[(rg * 8 + rr) * 36 + fq * 4];
      #pragma unroll
      for (int l = 0; l < 4; l++) {
        float4 wa = *(const float4*)&wS[(fq * 4 + l) * 64 + oc * 8];
        float4 wb = *(const float4*)&wS[(fq * 4 + l) * 64 + oc * 8 + 4];
        #pragma unroll
        for (int rr = 0; rr < 8; rr++) {
          float p = (l == 0) ? pv[rr].x : (l == 1) ? pv[rr].y
                   : (l == 2) ? pv[rr].z : pv[rr].w;
          acc[rr][0] += p * wa.x; acc[rr][1] += p * wa.y;
          acc[rr][2] += p * wa.z; acc[rr][3] += p * wa.w;
          acc[rr][4] += p * wb.x; acc[rr][5] += p * wb.y;
          acc[rr][6] += p * wb.z; acc[rr][7] += p * wb.w;
        }
      }
    }
    __syncthreads();
  }

  #pragma unroll
  for (int rr = 0; rr < 8; rr++) {
    int t = (rg * 8 + rr) * N_ + n;
    #pragma unroll
    for (int oo = 0; oo < 8; oo++)
      atomicAdd(&feats[(size_t)t * FD_ + oc * 8 + oo], acc[rr][oo]);
  }
}

// ---------------------------------------------------------------------------
// K3: fused per-graph GCN + mean-pool + MLP head. One block per graph.
// Aggregates feats over edges FIRST (linearity), then one [68,64]@[64,128]
// GEMM, relu, pool, 2-layer MLP.
// ---------------------------------------------------------------------------
__global__ __launch_bounds__(256) void gcn_head_kernel(
    const float* __restrict__ feats, const int* __restrict__ edge_index,
    const float* __restrict__ lin1_b, const float* __restrict__ gcn_w,
    const float* __restrict__ gcn_b, const float* __restrict__ w1,
    const float* __restrict__ b1, const float* __restrict__ w2,
    const float* __restrict__ b2, float* __restrict__ out) {
  const int b = blockIdx.x;
  const int tid = threadIdx.x;

  __shared__ float fS[N_ * 68];      // feats, pitch 68
  __shared__ float aS[N_ * 68];      // aggregated, pitch 68
  __shared__ float wS[FD_ * GH_];    // gcn_w [64][128], 32 KB
  __shared__ float gS[GH_];
  __shared__ float z1S[64];
  __shared__ int   degS[N_];
  __shared__ float disS[N_];

  // phase A: zero deg/g, load feats (finish lin1: +bias, relu), stage gcn_w
  if (tid < N_) degS[tid] = 0;
  if (tid < GH_) gS[tid] = 0.0f;
  for (int idx = tid; idx < N_ * FD_; idx += 256) {
    int i = idx >> 6, f = idx & 63;
    fS[i * 68 + f] = fmaxf(feats[(size_t)(b * N_ + i) * FD_ + f] + lin1_b[idx], 0.0f);
  }
  #pragma unroll
  for (int j = 0; j < 8; j++)
    ((float4*)wS)[tid + j * 256] = ((const float4*)gcn_w)[tid + j * 256];
  __syncthreads();

  const int* srcp = edge_index;
  const int* dstp = edge_index + (B_ * EG_);
  const int e0 = b * EG_;
  const int nbase = b * N_;

  for (int e = tid; e < EG_; e += 256)
    atomicAdd(&degS[dstp[e0 + e] - nbase], 1);
  __syncthreads();
  if (tid < N_) disS[tid] = rsqrtf((float)(degS[tid] + 1));   // +1 self-loop
  __syncthreads();

  // self-loop init of aggregation
  for (int idx = tid; idx < N_ * FD_; idx += 256) {
    int i = idx >> 6, f = idx & 63;
    float d = disS[i];
    aS[i * 68 + f] = d * d * fS[i * 68 + f];
  }
  __syncthreads();

  // edge scatter: aS[dst] += dis[src]*dis[dst]*fS[src]
  for (int idx = tid; idx < EG_ * FD_; idx += 256) {
    int e = idx >> 6, f = idx & 63;
    int ls = srcp[e0 + e] - nbase, ld = dstp[e0 + e] - nbase;
    float norm = disS[ls] * disS[ld];
    atomicAdd(&aS[ld * 68 + f], norm * fS[ls * 68 + f]);
  }
  __syncthreads();

  // GEMM [68,64] @ [64,128] + gcn_b, relu, accumulate column sums into gS
  const int jg = tid & 15;    // j0 = jg*8
  const int ig = tid >> 4;    // i base = ig*4
  #pragma unroll
  for (int sweep = 0; sweep < 2; sweep++) {
    int ibase = sweep * 64 + ig * 4;
    if (ibase < N_) {
      float acc[4][8];
      #pragma unroll
      for (int a = 0; a < 4; a++)
        #pragma unroll
        for (int c = 0; c < 8; c++) acc[a][c] = 0.0f;
      #pragma unroll 4
      for (int fq = 0; fq < 16; fq++) {
        float4 av[4];
        #pragma unroll
        for (int ii = 0; ii < 4; ii++)
          av[ii] = *(const float4*)&aS[(ibase + ii) * 68 + fq * 4];
        #pragma unroll
        for (int l = 0; l < 4; l++) {
          float4 wa = *(const float4*)&wS[(fq * 4 + l) * GH_ + jg * 8];
          float4 wb = *(const float4*)&wS[(fq * 4 + l) * GH_ + jg * 8 + 4];
          #pragma unroll
          for (int ii = 0; ii < 4; ii++) {
            float p = (l == 0) ? av[ii].x : (l == 1) ? av[ii].y
                     : (l == 2) ? av[ii].z : av[ii].w;
            acc[ii][0] += p * wa.x; acc[ii][1] += p * wa.y;
            acc[ii][2] += p * wa.z; acc[ii][3] += p * wa.w;
            acc[ii][4] += p * wb.x; acc[ii][5] += p * wb.y;
            acc[ii][6] += p * wb.z; acc[ii][7] += p * wb.w;
          }
        }
      }
      #pragma unroll
      for (int jj = 0; jj < 8; jj++) {
        float bias = gcn_b[jg * 8 + jj];
        float s = 0.0f;
        #pragma unroll
        for (int ii = 0; ii < 4; ii++)
          if (ibase + ii < N_) s += fmaxf(acc[ii][jj] + bias, 0.0f);
        atomicAdd(&gS[jg * 8 + jj], s);
      }
    }
  }
  __syncthreads();

  // MLP head
  if (tid < 64) {
    float s = b1[tid];
    #pragma unroll 8
    for (int j = 0; j < GH_; j++)
      s += (gS[j] * (1.0f / 68.0f)) * w1[j * 64 + tid];
    z1S[tid] = fmaxf(s, 0.0f);
  }
  __syncthreads();
  if (tid < 2) {
    float s = b2[tid];
    #pragma unroll 8
    for (int j = 0; j < 64; j++) s += z1S[j] * w2[j * 2 + tid];
    out[b * 2 + tid] = s;
  }
}

// ---------------------------------------------------------------------------
extern "C" void kernel_launch(void* const* d_in, const int* in_sizes, int n_in,
                              void* d_out, int out_size, void* d_ws, size_t ws_size,
                              hipStream_t stream) {
  const float* x        = (const float*)d_in[0];
  const int*   edge_idx = (const int*)d_in[1];
  // d_in[2] = batch (layout is known: t -> t/N), unused
  const float* conv_w   = (const float*)d_in[3];
  const float* conv_b   = (const float*)d_in[4];
  const float* lin1_w   = (const float*)d_in[5];
  const float* lin1_b   = (const float*)d_in[6];
  const float* gcn_w    = (const float*)d_in[7];
  const float* gcn_b    = (const float*)d_in[8];
  const float* mlp_w1   = (const float*)d_in[9];
  const float* mlp_b1   = (const float*)d_in[10];
  const float* mlp_w2   = (const float*)d_in[11];
  const float* mlp_b2   = (const float*)d_in[12];
  float* outp = (float*)d_out;

  float* pooled = (float*)d_ws;                       // T*4096 fp32 = 142.6 MB
  float* feats  = pooled + (size_t)T_ * FLAT_;        // T*64 fp32  =   2.2 MB

  hipMemsetAsync(feats, 0, (size_t)T_ * FD_ * sizeof(float), stream);

  conv_pool_kernel<<<T_, 256, 0, stream>>>(x, conv_w, conv_b, pooled);
  lin1_kernel<<<N_ * 8, 128, 0, stream>>>(pooled, lin1_w, feats);
  gcn_head_kernel<<<B_, 256, 0, stream>>>(feats, edge_idx, lin1_b, gcn_w, gcn_b,
                                          mlp_w1, mlp_b1, mlp_w2, mlp_b2, outp);
}

// Round 2
// 417.175 us; speedup vs baseline: 1.2538x; 1.2538x over previous
//
#include <hip/hip_runtime.h>
#include <hip/hip_bf16.h>

// Problem constants
#define B_   128
#define N_   68
#define C_   3
#define P_   32
#define K_   16
#define FD_  64
#define GH_  128
#define EG_  544          // 8*N
#define T_   8704         // B*N
#define FLAT_ 4096        // K*16*16
#define FCH_ 8            // f-chunks in lin1 (K-split)

// ---------------------------------------------------------------------------
// K1: per-node conv3x3(SAME) + bias + relu + maxpool2x2 -> pooled[T][4096]
// One block per node (8704 blocks, 256 threads). x staged in zero-padded LDS.
// ---------------------------------------------------------------------------
__global__ __launch_bounds__(256) void conv_pool_kernel(
    const float* __restrict__ x, const float* __restrict__ conv_w,
    const float* __restrict__ conv_b, float* __restrict__ pooled) {
  const int t = blockIdx.x;
  const int n = t % N_;
  const int tid = threadIdx.x;

  __shared__ float xs[3 * 34 * 34];   // zero-padded [c][34][34]

  for (int i = tid; i < 3 * 34 * 34; i += 256) xs[i] = 0.0f;
  __syncthreads();

  const float4* xg = (const float4*)(x + (size_t)t * (C_ * P_ * P_));
  #pragma unroll
  for (int j = 0; j < 3; j++) {
    int i4 = tid + j * 256;          // 768 float4 total
    float4 v = xg[i4];
    int f0 = i4 * 4;
    int c = f0 >> 10, rem = f0 & 1023, y = rem >> 5, xc = rem & 31;
    float* dstp = &xs[c * 1156 + (y + 1) * 34 + xc + 1];
    dstp[0] = v.x; dstp[1] = v.y; dstp[2] = v.z; dstp[3] = v.w;
  }
  __syncthreads();

  const int py = tid >> 4, px = tid & 15;

  float xr[3][4][4];
  #pragma unroll
  for (int c = 0; c < 3; c++)
    #pragma unroll
    for (int r = 0; r < 4; r++)
      #pragma unroll
      for (int cc = 0; cc < 4; cc++)
        xr[c][r][cc] = xs[c * 1156 + (2 * py + r) * 34 + (2 * px + cc)];

  const float* wp = conv_w + (size_t)n * (K_ * 27);
  const float* bp = conv_b + (size_t)n * K_;
  float* outp = pooled + (size_t)t * FLAT_ + py * 16 + px;

  #pragma unroll 2
  for (int k = 0; k < K_; k++) {
    const float* wk = wp + k * 27;
    float bk = bp[k];
    float a00 = bk, a01 = bk, a10 = bk, a11 = bk;
    #pragma unroll
    for (int c = 0; c < 3; c++)
      #pragma unroll
      for (int dy = 0; dy < 3; dy++)
        #pragma unroll
        for (int dx = 0; dx < 3; dx++) {
          float w = wk[c * 9 + dy * 3 + dx];   // uniform -> SGPR
          a00 += xr[c][dy][dx]       * w;
          a01 += xr[c][dy][dx + 1]   * w;
          a10 += xr[c][dy + 1][dx]   * w;
          a11 += xr[c][dy + 1][dx + 1] * w;
        }
    float m = fmaxf(fmaxf(a00, a01), fmaxf(a10, a11));
    m = fmaxf(m, 0.0f);
    outp[k * 256] = m;
  }
}

// ---------------------------------------------------------------------------
// K2: per-type linear. Grid = 68 types x 8 f-chunks(512) x 2 row-halves(64)
// = 1088 blocks, 256 threads (~17 waves/CU vs 4.25 in R0 -- occupancy fix).
// Tile 64 rows x 64 outs, thread tile 4x4, K-tiles of 32 with b128 LDS reads.
// Writes DETERMINISTIC partials part[fc][t][64] (no atomics); gcn_head sums.
// ---------------------------------------------------------------------------
__global__ __launch_bounds__(256) void lin1_kernel(
    const float* __restrict__ pooled, const float* __restrict__ lin1_w,
    float* __restrict__ part) {
  const int bid = blockIdx.x;
  const int rh  = bid & 1;
  const int fc  = (bid >> 1) & 7;
  const int n   = bid >> 4;
  const int tid = threadIdx.x;
  const int tx  = tid & 15;      // outs o = tx*4 .. +3
  const int ty  = tid >> 4;      // rows r = r0 + ty*4 .. +3

  __shared__ float pS[64 * 40];  // 64 rows x 32 f, pitch 40 (16B-aligned, no conflicts)
  __shared__ float wS[32 * 64];  // 32 f x 64 outs

  float acc[4][4];
  #pragma unroll
  for (int a = 0; a < 4; a++)
    #pragma unroll
    for (int c = 0; c < 4; c++) acc[a][c] = 0.0f;

  const int r0 = rh * 64;
  const int f_base = fc * 512;

  for (int tile = 0; tile < 16; tile++) {
    const int f0 = f_base + tile * 32;
    // stage pooled tile: 512 float4, 2/thread
    #pragma unroll
    for (int j = 0; j < 2; j++) {
      int i4 = tid + j * 256;
      int r = i4 >> 3, qf = (i4 & 7) * 4;
      float4 v = *(const float4*)&pooled[(size_t)((r0 + r) * N_ + n) * FLAT_ + f0 + qf];
      *(float4*)&pS[r * 40 + qf] = v;
    }
    // stage w tile: 2048 contiguous floats, 2 float4/thread
    const float4* wg = (const float4*)&lin1_w[(size_t)n * (FLAT_ * FD_) + (size_t)f0 * FD_];
    #pragma unroll
    for (int j = 0; j < 2; j++) ((float4*)wS)[tid + j * 256] = wg[tid + j * 256];
    __syncthreads();

    #pragma unroll
    for (int fq = 0; fq < 8; fq++) {
      float4 pv[4];
      #pragma unroll
      for (int rr = 0; rr < 4; rr++)
        pv[rr] = *(const float4*)&pS[(ty * 4 + rr) * 40 + fq * 4];
      #pragma unroll
      for (int l = 0; l < 4; l++) {
        float4 wv = *(const float4*)&wS[(fq * 4 + l) * 64 + tx * 4];
        #pragma unroll
        for (int rr = 0; rr < 4; rr++) {
          float p = (l == 0) ? pv[rr].x : (l == 1) ? pv[rr].y
                   : (l == 2) ? pv[rr].z : pv[rr].w;
          acc[rr][0] += p * wv.x; acc[rr][1] += p * wv.y;
          acc[rr][2] += p * wv.z; acc[rr][3] += p * wv.w;
        }
      }
    }
    __syncthreads();
  }

  float* pb = part + (size_t)fc * T_ * FD_;
  #pragma unroll
  for (int rr = 0; rr < 4; rr++) {
    int t = (r0 + ty * 4 + rr) * N_ + n;
    float4 v; v.x = acc[rr][0]; v.y = acc[rr][1]; v.z = acc[rr][2]; v.w = acc[rr][3];
    *(float4*)&pb[(size_t)t * FD_ + tx * 4] = v;
  }
}

// ---------------------------------------------------------------------------
// K3: fused per-graph GCN + mean-pool + MLP head. One block per graph.
// Sums the 8 lin1 partials on load (+bias, relu), aggregates feats over edges
// (linearity), then [68,64]@[64,128] GEMM, relu, pool, 2-layer MLP.
// ---------------------------------------------------------------------------
__global__ __launch_bounds__(256) void gcn_head_kernel(
    const float* __restrict__ part, const int* __restrict__ edge_index,
    const float* __restrict__ lin1_b, const float* __restrict__ gcn_w,
    const float* __restrict__ gcn_b, const float* __restrict__ w1,
    const float* __restrict__ b1, const float* __restrict__ w2,
    const float* __restrict__ b2, float* __restrict__ out) {
  const int b = blockIdx.x;
  const int tid = threadIdx.x;

  __shared__ float fS[N_ * 68];      // feats, pitch 68
  __shared__ float aS[N_ * 68];      // aggregated, pitch 68
  __shared__ float wS[FD_ * GH_];    // gcn_w [64][128], 32 KB
  __shared__ float gS[GH_];
  __shared__ float z1S[64];
  __shared__ int   degS[N_];
  __shared__ float disS[N_];

  if (tid < N_) degS[tid] = 0;
  if (tid < GH_) gS[tid] = 0.0f;
  // load feats: sum 8 partials + bias, relu (float4 over N*FD)
  for (int idx4 = tid; idx4 < (N_ * FD_) / 4; idx4 += 256) {
    int i  = idx4 >> 4;            // node
    int f4 = (idx4 & 15) * 4;      // feature quad
    int t  = b * N_ + i;
    float4 s = *(const float4*)&lin1_b[i * FD_ + f4];
    #pragma unroll
    for (int fc = 0; fc < FCH_; fc++) {
      float4 v = *(const float4*)&part[((size_t)fc * T_ + t) * FD_ + f4];
      s.x += v.x; s.y += v.y; s.z += v.z; s.w += v.w;
    }
    s.x = fmaxf(s.x, 0.0f); s.y = fmaxf(s.y, 0.0f);
    s.z = fmaxf(s.z, 0.0f); s.w = fmaxf(s.w, 0.0f);
    *(float4*)&fS[i * 68 + f4] = s;
  }
  #pragma unroll
  for (int j = 0; j < 8; j++)
    ((float4*)wS)[tid + j * 256] = ((const float4*)gcn_w)[tid + j * 256];
  __syncthreads();

  const int* srcp = edge_index;
  const int* dstp = edge_index + (B_ * EG_);
  const int e0 = b * EG_;
  const int nbase = b * N_;

  for (int e = tid; e < EG_; e += 256)
    atomicAdd(&degS[dstp[e0 + e] - nbase], 1);
  __syncthreads();
  if (tid < N_) disS[tid] = rsqrtf((float)(degS[tid] + 1));   // +1 self-loop
  __syncthreads();

  // self-loop init of aggregation
  for (int idx = tid; idx < N_ * FD_; idx += 256) {
    int i = idx >> 6, f = idx & 63;
    float d = disS[i];
    aS[i * 68 + f] = d * d * fS[i * 68 + f];
  }
  __syncthreads();

  // edge scatter: aS[dst] += dis[src]*dis[dst]*fS[src]
  for (int idx = tid; idx < EG_ * FD_; idx += 256) {
    int e = idx >> 6, f = idx & 63;
    int ls = srcp[e0 + e] - nbase, ld = dstp[e0 + e] - nbase;
    float norm = disS[ls] * disS[ld];
    atomicAdd(&aS[ld * 68 + f], norm * fS[ls * 68 + f]);
  }
  __syncthreads();

  // GEMM [68,64] @ [64,128] + gcn_b, relu, accumulate column sums into gS
  const int jg = tid & 15;    // j0 = jg*8
  const int ig = tid >> 4;    // i base = ig*4
  #pragma unroll
  for (int sweep = 0; sweep < 2; sweep++) {
    int ibase = sweep * 64 + ig * 4;
    if (ibase < N_) {
      float acc[4][8];
      #pragma unroll
      for (int a = 0; a < 4; a++)
        #pragma unroll
        for (int c = 0; c < 8; c++) acc[a][c] = 0.0f;
      #pragma unroll 4
      for (int fq = 0; fq < 16; fq++) {
        float4 av[4];
        #pragma unroll
        for (int ii = 0; ii < 4; ii++)
          av[ii] = *(const float4*)&aS[(ibase + ii) * 68 + fq * 4];
        #pragma unroll
        for (int l = 0; l < 4; l++) {
          float4 wa = *(const float4*)&wS[(fq * 4 + l) * GH_ + jg * 8];
          float4 wb = *(const float4*)&wS[(fq * 4 + l) * GH_ + jg * 8 + 4];
          #pragma unroll
          for (int ii = 0; ii < 4; ii++) {
            float p = (l == 0) ? av[ii].x : (l == 1) ? av[ii].y
                     : (l == 2) ? av[ii].z : av[ii].w;
            acc[ii][0] += p * wa.x; acc[ii][1] += p * wa.y;
            acc[ii][2] += p * wa.z; acc[ii][3] += p * wa.w;
            acc[ii][4] += p * wb.x; acc[ii][5] += p * wb.y;
            acc[ii][6] += p * wb.z; acc[ii][7] += p * wb.w;
          }
        }
      }
      #pragma unroll
      for (int jj = 0; jj < 8; jj++) {
        float bias = gcn_b[jg * 8 + jj];
        float s = 0.0f;
        #pragma unroll
        for (int ii = 0; ii < 4; ii++)
          if (ibase + ii < N_) s += fmaxf(acc[ii][jj] + bias, 0.0f);
        atomicAdd(&gS[jg * 8 + jj], s);
      }
    }
  }
  __syncthreads();

  // MLP head
  if (tid < 64) {
    float s = b1[tid];
    #pragma unroll 8
    for (int j = 0; j < GH_; j++)
      s += (gS[j] * (1.0f / 68.0f)) * w1[j * 64 + tid];
    z1S[tid] = fmaxf(s, 0.0f);
  }
  __syncthreads();
  if (tid < 2) {
    float s = b2[tid];
    #pragma unroll 8
    for (int j = 0; j < 64; j++) s += z1S[j] * w2[j * 2 + tid];
    out[b * 2 + tid] = s;
  }
}

// ---------------------------------------------------------------------------
extern "C" void kernel_launch(void* const* d_in, const int* in_sizes, int n_in,
                              void* d_out, int out_size, void* d_ws, size_t ws_size,
                              hipStream_t stream) {
  const float* x        = (const float*)d_in[0];
  const int*   edge_idx = (const int*)d_in[1];
  // d_in[2] = batch (layout known: t -> t/N), unused
  const float* conv_w   = (const float*)d_in[3];
  const float* conv_b   = (const float*)d_in[4];
  const float* lin1_w   = (const float*)d_in[5];
  const float* lin1_b   = (const float*)d_in[6];
  const float* gcn_w    = (const float*)d_in[7];
  const float* gcn_b    = (const float*)d_in[8];
  const float* mlp_w1   = (const float*)d_in[9];
  const float* mlp_b1   = (const float*)d_in[10];
  const float* mlp_w2   = (const float*)d_in[11];
  const float* mlp_b2   = (const float*)d_in[12];
  float* outp = (float*)d_out;

  float* pooled = (float*)d_ws;                       // T*4096 fp32 = 142.6 MB
  float* part   = pooled + (size_t)T_ * FLAT_;        // 8*T*64 fp32 = 17.8 MB

  conv_pool_kernel<<<T_, 256, 0, stream>>>(x, conv_w, conv_b, pooled);
  lin1_kernel<<<N_ * FCH_ * 2, 256, 0, stream>>>(pooled, lin1_w, part);
  gcn_head_kernel<<<B_, 256, 0, stream>>>(part, edge_idx, lin1_b, gcn_w, gcn_b,
                                          mlp_w1, mlp_b1, mlp_w2, mlp_b2, outp);
}

// Round 3
// 388.940 us; speedup vs baseline: 1.3449x; 1.0726x over previous
//
#include <hip/hip_runtime.h>
#include <hip/hip_fp16.h>

// Problem constants
#define B_   128
#define N_   68
#define C_   3
#define P_   32
#define K_   16
#define FD_  64
#define GH_  128
#define EG_  544          // 8*N
#define T_   8704         // B*N
#define FLAT_ 4096        // K*16*16
#define FCH_ 8            // f-chunks in lin1 (K-split of 512)

typedef __attribute__((ext_vector_type(8))) _Float16 half8;
typedef __attribute__((ext_vector_type(4))) float   floatx4;

// ---------------------------------------------------------------------------
// K1: per-node conv3x3(SAME) + bias + relu + maxpool2x2 -> pooled[T][4096] fp16
// One block per node (8704 blocks, 256 threads). x staged in zero-padded LDS.
// Border-only zeroing (disjoint from interior scatter -> single barrier).
// ---------------------------------------------------------------------------
__global__ __launch_bounds__(256) void conv_pool_kernel(
    const float* __restrict__ x, const float* __restrict__ conv_w,
    const float* __restrict__ conv_b, _Float16* __restrict__ pooled) {
  const int t = blockIdx.x;
  const int n = t % N_;
  const int tid = threadIdx.x;

  __shared__ float xs[3 * 34 * 34];   // zero-padded [c][34][34]

  // zero only the 1-wide border (396 elems); interior is fully overwritten
  for (int i = tid; i < 396; i += 256) {
    int c = i / 132, j = i - c * 132;
    int off;
    if (j < 34)       off = j;                       // top row
    else if (j < 68)  off = 33 * 34 + (j - 34);      // bottom row
    else if (j < 100) off = (j - 68 + 1) * 34;       // left col
    else              off = (j - 100 + 1) * 34 + 33; // right col
    xs[c * 1156 + off] = 0.0f;
  }

  const float4* xg = (const float4*)(x + (size_t)t * (C_ * P_ * P_));
  #pragma unroll
  for (int j = 0; j < 3; j++) {
    int i4 = tid + j * 256;          // 768 float4 total
    float4 v = xg[i4];
    int f0 = i4 * 4;
    int c = f0 >> 10, rem = f0 & 1023, y = rem >> 5, xc = rem & 31;
    float* dstp = &xs[c * 1156 + (y + 1) * 34 + xc + 1];
    dstp[0] = v.x; dstp[1] = v.y; dstp[2] = v.z; dstp[3] = v.w;
  }
  __syncthreads();

  const int py = tid >> 4, px = tid & 15;

  float xr[3][4][4];
  #pragma unroll
  for (int c = 0; c < 3; c++)
    #pragma unroll
    for (int r = 0; r < 4; r++)
      #pragma unroll
      for (int cc = 0; cc < 4; cc++)
        xr[c][r][cc] = xs[c * 1156 + (2 * py + r) * 34 + (2 * px + cc)];

  const float* wp = conv_w + (size_t)n * (K_ * 27);
  const float* bp = conv_b + (size_t)n * K_;
  _Float16* outp = pooled + (size_t)t * FLAT_ + py * 16 + px;

  #pragma unroll 2
  for (int k = 0; k < K_; k++) {
    const float* wk = wp + k * 27;
    float bk = bp[k];
    float a00 = bk, a01 = bk, a10 = bk, a11 = bk;
    #pragma unroll
    for (int c = 0; c < 3; c++)
      #pragma unroll
      for (int dy = 0; dy < 3; dy++)
        #pragma unroll
        for (int dx = 0; dx < 3; dx++) {
          float w = wk[c * 9 + dy * 3 + dx];   // uniform -> SGPR
          a00 += xr[c][dy][dx]         * w;
          a01 += xr[c][dy][dx + 1]     * w;
          a10 += xr[c][dy + 1][dx]     * w;
          a11 += xr[c][dy + 1][dx + 1] * w;
        }
    float m = fmaxf(fmaxf(a00, a01), fmaxf(a10, a11));
    m = fmaxf(m, 0.0f);
    outp[k * 256] = (_Float16)m;
  }
}

// ---------------------------------------------------------------------------
// K2: per-type linear via fp16 MFMA 16x16x32. Grid = 68 types x 8 f-chunks
// (K=512 each) = 544 blocks, 256 threads (4 waves). Wave handles 32 rows x
// 64 outs = 2x4 frags. K-steps of 64 (2 MFMA k-halves). lin1_w converted
// fp32->fp16 + transposed into LDS during staging.
// Writes DETERMINISTIC partials part[fc][t][64] fp32; gcn_head sums.
// ---------------------------------------------------------------------------
__global__ __launch_bounds__(256) void lin1_mfma_kernel(
    const _Float16* __restrict__ pooled, const float* __restrict__ lin1_w,
    float* __restrict__ part) {
  const int n   = blockIdx.x >> 3;
  const int fc  = blockIdx.x & 7;
  const int tid = threadIdx.x;
  const int wave = tid >> 6, lane = tid & 63;
  const int q = lane >> 4, lr = lane & 15;

  // pitch 72 fp16 (144 B): frag b128 reads land 2-way on banks (free), 16B-aligned
  __shared__ __align__(16) _Float16 As[128 * 72];  // 128 rows x 64 k
  __shared__ __align__(16) _Float16 Bt[64 * 72];   // 64 outs x 64 k (transposed w)

  floatx4 acc[2][4];
  #pragma unroll
  for (int mt = 0; mt < 2; mt++)
    #pragma unroll
    for (int nt = 0; nt < 4; nt++)
      acc[mt][nt] = (floatx4){0.f, 0.f, 0.f, 0.f};

  const int f_base = fc * 512;
  for (int step = 0; step < 8; step++) {
    const int f0 = f_base + step * 64;

    // stage A: 128 rows x 64 fp16 (128 B/row); 1024 16B-chunks, 4/thread
    #pragma unroll
    for (int j = 0; j < 4; j++) {
      int idx = tid + j * 256;
      int r = idx >> 3, ch = idx & 7;
      uint4 v = *(const uint4*)&pooled[(size_t)(r * N_ + n) * FLAT_ + f0 + ch * 8];
      *(uint4*)&As[r * 72 + ch * 8] = v;
    }
    // stage B: w slice [64 k][64 o] = 4096 contiguous floats; cvt + transpose
    const float* wg = &lin1_w[(size_t)n * (FLAT_ * FD_) + (size_t)f0 * FD_];
    #pragma unroll
    for (int j = 0; j < 4; j++) {
      int idx4 = tid + j * 256;
      float4 v = *(const float4*)&wg[idx4 * 4];
      int flat = idx4 * 4;
      int k = flat >> 6, o = flat & 63;
      Bt[(o + 0) * 72 + k] = (_Float16)v.x;
      Bt[(o + 1) * 72 + k] = (_Float16)v.y;
      Bt[(o + 2) * 72 + k] = (_Float16)v.z;
      Bt[(o + 3) * 72 + k] = (_Float16)v.w;
    }
    __syncthreads();

    #pragma unroll
    for (int kh = 0; kh < 2; kh++) {
      half8 af[2], bf[4];
      #pragma unroll
      for (int mt = 0; mt < 2; mt++)
        af[mt] = *(const half8*)&As[(wave * 32 + mt * 16 + lr) * 72 + kh * 32 + q * 8];
      #pragma unroll
      for (int nt = 0; nt < 4; nt++)
        bf[nt] = *(const half8*)&Bt[(nt * 16 + lr) * 72 + kh * 32 + q * 8];
      #pragma unroll
      for (int mt = 0; mt < 2; mt++)
        #pragma unroll
        for (int nt = 0; nt < 4; nt++)
          acc[mt][nt] = __builtin_amdgcn_mfma_f32_16x16x32_f16(
              af[mt], bf[nt], acc[mt][nt], 0, 0, 0);
    }
    __syncthreads();
  }

  // store partials: D layout col=lane&15, row=quad*4+reg
  float* pb = part + (size_t)fc * T_ * FD_;
  #pragma unroll
  for (int mt = 0; mt < 2; mt++) {
    #pragma unroll
    for (int v = 0; v < 4; v++) {
      int r = wave * 32 + mt * 16 + q * 4 + v;
      size_t base = (size_t)(r * N_ + n) * FD_;
      #pragma unroll
      for (int nt = 0; nt < 4; nt++)
        pb[base + nt * 16 + lr] = acc[mt][nt][v];
    }
  }
}

// ---------------------------------------------------------------------------
// K3: fused per-graph GCN + mean-pool + MLP head. One block per graph.
// Sums the 8 lin1 partials on load (+bias, relu), aggregates feats over edges
// (linearity), then [68,64]@[64,128] GEMM, relu, pool, 2-layer MLP.
// ---------------------------------------------------------------------------
__global__ __launch_bounds__(256) void gcn_head_kernel(
    const float* __restrict__ part, const int* __restrict__ edge_index,
    const float* __restrict__ lin1_b, const float* __restrict__ gcn_w,
    const float* __restrict__ gcn_b, const float* __restrict__ w1,
    const float* __restrict__ b1, const float* __restrict__ w2,
    const float* __restrict__ b2, float* __restrict__ out) {
  const int b = blockIdx.x;
  const int tid = threadIdx.x;

  __shared__ float fS[N_ * 68];      // feats, pitch 68
  __shared__ float aS[N_ * 68];      // aggregated, pitch 68
  __shared__ float wS[FD_ * GH_];    // gcn_w [64][128], 32 KB
  __shared__ float gS[GH_];
  __shared__ float z1S[64];
  __shared__ int   degS[N_];
  __shared__ float disS[N_];

  if (tid < N_) degS[tid] = 0;
  if (tid < GH_) gS[tid] = 0.0f;
  // load feats: sum 8 partials + bias, relu (float4 over N*FD)
  for (int idx4 = tid; idx4 < (N_ * FD_) / 4; idx4 += 256) {
    int i  = idx4 >> 4;            // node
    int f4 = (idx4 & 15) * 4;      // feature quad
    int t  = b * N_ + i;
    float4 s = *(const float4*)&lin1_b[i * FD_ + f4];
    #pragma unroll
    for (int fc = 0; fc < FCH_; fc++) {
      float4 v = *(const float4*)&part[((size_t)fc * T_ + t) * FD_ + f4];
      s.x += v.x; s.y += v.y; s.z += v.z; s.w += v.w;
    }
    s.x = fmaxf(s.x, 0.0f); s.y = fmaxf(s.y, 0.0f);
    s.z = fmaxf(s.z, 0.0f); s.w = fmaxf(s.w, 0.0f);
    *(float4*)&fS[i * 68 + f4] = s;
  }
  #pragma unroll
  for (int j = 0; j < 8; j++)
    ((float4*)wS)[tid + j * 256] = ((const float4*)gcn_w)[tid + j * 256];
  __syncthreads();

  const int* srcp = edge_index;
  const int* dstp = edge_index + (B_ * EG_);
  const int e0 = b * EG_;
  const int nbase = b * N_;

  for (int e = tid; e < EG_; e += 256)
    atomicAdd(&degS[dstp[e0 + e] - nbase], 1);
  __syncthreads();
  if (tid < N_) disS[tid] = rsqrtf((float)(degS[tid] + 1));   // +1 self-loop
  __syncthreads();

  // self-loop init of aggregation
  for (int idx = tid; idx < N_ * FD_; idx += 256) {
    int i = idx >> 6, f = idx & 63;
    float d = disS[i];
    aS[i * 68 + f] = d * d * fS[i * 68 + f];
  }
  __syncthreads();

  // edge scatter: aS[dst] += dis[src]*dis[dst]*fS[src]
  for (int idx = tid; idx < EG_ * FD_; idx += 256) {
    int e = idx >> 6, f = idx & 63;
    int ls = srcp[e0 + e] - nbase, ld = dstp[e0 + e] - nbase;
    float norm = disS[ls] * disS[ld];
    atomicAdd(&aS[ld * 68 + f], norm * fS[ls * 68 + f]);
  }
  __syncthreads();

  // GEMM [68,64] @ [64,128] + gcn_b, relu, accumulate column sums into gS
  const int jg = tid & 15;    // j0 = jg*8
  const int ig = tid >> 4;    // i base = ig*4
  #pragma unroll
  for (int sweep = 0; sweep < 2; sweep++) {
    int ibase = sweep * 64 + ig * 4;
    if (ibase < N_) {
      float acc[4][8];
      #pragma unroll
      for (int a = 0; a < 4; a++)
        #pragma unroll
        for (int c = 0; c < 8; c++) acc[a][c] = 0.0f;
      #pragma unroll 4
      for (int fq = 0; fq < 16; fq++) {
        float4 av[4];
        #pragma unroll
        for (int ii = 0; ii < 4; ii++)
          av[ii] = *(const float4*)&aS[(ibase + ii) * 68 + fq * 4];
        #pragma unroll
        for (int l = 0; l < 4; l++) {
          float4 wa = *(const float4*)&wS[(fq * 4 + l) * GH_ + jg * 8];
          float4 wb = *(const float4*)&wS[(fq * 4 + l) * GH_ + jg * 8 + 4];
          #pragma unroll
          for (int ii = 0; ii < 4; ii++) {
            float p = (l == 0) ? av[ii].x : (l == 1) ? av[ii].y
                     : (l == 2) ? av[ii].z : av[ii].w;
            acc[ii][0] += p * wa.x; acc[ii][1] += p * wa.y;
            acc[ii][2] += p * wa.z; acc[ii][3] += p * wa.w;
            acc[ii][4] += p * wb.x; acc[ii][5] += p * wb.y;
            acc[ii][6] += p * wb.z; acc[ii][7] += p * wb.w;
          }
        }
      }
      #pragma unroll
      for (int jj = 0; jj < 8; jj++) {
        float bias = gcn_b[jg * 8 + jj];
        float s = 0.0f;
        #pragma unroll
        for (int ii = 0; ii < 4; ii++)
          if (ibase + ii < N_) s += fmaxf(acc[ii][jj] + bias, 0.0f);
        atomicAdd(&gS[jg * 8 + jj], s);
      }
    }
  }
  __syncthreads();

  // MLP head
  if (tid < 64) {
    float s = b1[tid];
    #pragma unroll 8
    for (int j = 0; j < GH_; j++)
      s += (gS[j] * (1.0f / 68.0f)) * w1[j * 64 + tid];
    z1S[tid] = fmaxf(s, 0.0f);
  }
  __syncthreads();
  if (tid < 2) {
    float s = b2[tid];
    #pragma unroll 8
    for (int j = 0; j < 64; j++) s += z1S[j] * w2[j * 2 + tid];
    out[b * 2 + tid] = s;
  }
}

// ---------------------------------------------------------------------------
extern "C" void kernel_launch(void* const* d_in, const int* in_sizes, int n_in,
                              void* d_out, int out_size, void* d_ws, size_t ws_size,
                              hipStream_t stream) {
  const float* x        = (const float*)d_in[0];
  const int*   edge_idx = (const int*)d_in[1];
  // d_in[2] = batch (layout known: t -> t/N), unused
  const float* conv_w   = (const float*)d_in[3];
  const float* conv_b   = (const float*)d_in[4];
  const float* lin1_w   = (const float*)d_in[5];
  const float* lin1_b   = (const float*)d_in[6];
  const float* gcn_w    = (const float*)d_in[7];
  const float* gcn_b    = (const float*)d_in[8];
  const float* mlp_w1   = (const float*)d_in[9];
  const float* mlp_b1   = (const float*)d_in[10];
  const float* mlp_w2   = (const float*)d_in[11];
  const float* mlp_b2   = (const float*)d_in[12];
  float* outp = (float*)d_out;

  _Float16* pooled = (_Float16*)d_ws;                       // T*4096 fp16 = 71.3 MB
  float* part = (float*)((char*)d_ws + (size_t)T_ * FLAT_ * 2);  // 8*T*64 fp32 = 17.8 MB

  conv_pool_kernel<<<T_, 256, 0, stream>>>(x, conv_w, conv_b, pooled);
  lin1_mfma_kernel<<<N_ * FCH_, 256, 0, stream>>>(pooled, lin1_w, part);
  gcn_head_kernel<<<B_, 256, 0, stream>>>(part, edge_idx, lin1_b, gcn_w, gcn_b,
                                          mlp_w1, mlp_b1, mlp_w2, mlp_b2, outp);
}

// Round 4
// 355.653 us; speedup vs baseline: 1.4707x; 1.0936x over previous
//
#include <hip/hip_runtime.h>
#include <hip/hip_fp16.h>

// Problem constants
#define B_   128
#define N_   68
#define C_   3
#define P_   32
#define K_   16
#define FD_  64
#define GH_  128
#define EG_  544          // 8*N
#define T_   8704         // B*N
#define FLAT_ 4096        // K*16*16
#define FCH_ 16           // f-chunks in lin1 (K-split of 256)

typedef __attribute__((ext_vector_type(8))) _Float16 half8;
typedef __attribute__((ext_vector_type(2))) _Float16 half2v;
typedef __attribute__((ext_vector_type(4))) float   floatx4;

// ---------------------------------------------------------------------------
// K1: per-node conv3x3(SAME) + bias + relu + maxpool2x2 -> pooled[T][4096] fp16
// One block per node. Weights staged in LDS (removes per-k scalar-load stall);
// per-k they reach the FMAs via 7 broadcast ds_read_b128.
// ---------------------------------------------------------------------------
__global__ __launch_bounds__(256) void conv_pool_kernel(
    const float* __restrict__ x, const float* __restrict__ conv_w,
    const float* __restrict__ conv_b, _Float16* __restrict__ pooled) {
  const int t = blockIdx.x;
  const int n = t % N_;
  const int tid = threadIdx.x;

  __shared__ float xs[3 * 34 * 34];   // zero-padded [c][34][34]
  __shared__ float wS[K_ * 28];       // [k][28]: 27 weights + bias

  // stage weights+bias
  {
    const float* wp = conv_w + (size_t)n * (K_ * 27);
    const float* bp = conv_b + (size_t)n * K_;
    for (int i = tid; i < K_ * 28; i += 256) {
      int k = i / 28, j = i - k * 28;
      wS[i] = (j < 27) ? wp[k * 27 + j] : bp[k];
    }
  }
  // zero only the 1-wide border (interior fully overwritten)
  for (int i = tid; i < 396; i += 256) {
    int c = i / 132, j = i - c * 132;
    int off;
    if (j < 34)       off = j;                       // top row
    else if (j < 68)  off = 33 * 34 + (j - 34);      // bottom row
    else if (j < 100) off = (j - 68 + 1) * 34;       // left col
    else              off = (j - 100 + 1) * 34 + 33; // right col
    xs[c * 1156 + off] = 0.0f;
  }
  const float4* xg = (const float4*)(x + (size_t)t * (C_ * P_ * P_));
  #pragma unroll
  for (int j = 0; j < 3; j++) {
    int i4 = tid + j * 256;          // 768 float4 total
    float4 v = xg[i4];
    int f0 = i4 * 4;
    int c = f0 >> 10, rem = f0 & 1023, y = rem >> 5, xc = rem & 31;
    float* dstp = &xs[c * 1156 + (y + 1) * 34 + xc + 1];
    dstp[0] = v.x; dstp[1] = v.y; dstp[2] = v.z; dstp[3] = v.w;
  }
  __syncthreads();

  const int py = tid >> 4, px = tid & 15;

  float xr[3][4][4];
  #pragma unroll
  for (int c = 0; c < 3; c++)
    #pragma unroll
    for (int r = 0; r < 4; r++)
      #pragma unroll
      for (int cc = 0; cc < 4; cc++)
        xr[c][r][cc] = xs[c * 1156 + (2 * py + r) * 34 + (2 * px + cc)];

  _Float16* outp = pooled + (size_t)t * FLAT_ + py * 16 + px;

  #pragma unroll 2
  for (int k = 0; k < K_; k++) {
    float w[28];
    const float4* wk4 = (const float4*)&wS[k * 28];
    #pragma unroll
    for (int q4 = 0; q4 < 7; q4++) *(float4*)&w[q4 * 4] = wk4[q4];  // broadcast
    float bk = w[27];
    float a00 = bk, a01 = bk, a10 = bk, a11 = bk;
    #pragma unroll
    for (int c = 0; c < 3; c++)
      #pragma unroll
      for (int dy = 0; dy < 3; dy++)
        #pragma unroll
        for (int dx = 0; dx < 3; dx++) {
          float wv = w[c * 9 + dy * 3 + dx];
          a00 += xr[c][dy][dx]         * wv;
          a01 += xr[c][dy][dx + 1]     * wv;
          a10 += xr[c][dy + 1][dx]     * wv;
          a11 += xr[c][dy + 1][dx + 1] * wv;
        }
    float m = fmaxf(fmaxf(a00, a01), fmaxf(a10, a11));
    m = fmaxf(m, 0.0f);
    outp[k * 256] = (_Float16)m;
  }
}

// ---------------------------------------------------------------------------
// K2: per-type linear via fp16 MFMA 16x16x32. Grid = 68 types x 16 f-chunks
// (K=256 each) = 1088 blocks, 256 threads. Wave: 32 rows x 64 outs (2x4
// frags). 4 K-steps of 64. B transposed into LDS via packed half2 writes.
// Writes DETERMINISTIC partials part[fc][t][64] fp32.
// ---------------------------------------------------------------------------
__global__ __launch_bounds__(256) void lin1_mfma_kernel(
    const _Float16* __restrict__ pooled, const float* __restrict__ lin1_w,
    float* __restrict__ part) {
  const int n   = blockIdx.x >> 4;
  const int fc  = blockIdx.x & 15;
  const int tid = threadIdx.x;
  const int wave = tid >> 6, lane = tid & 63;
  const int q = lane >> 4, lr = lane & 15;

  __shared__ __align__(16) _Float16 As[128 * 72];  // 128 rows x 64 k, pitch 72
  __shared__ __align__(16) _Float16 Bt[64 * 72];   // 64 outs x 64 k

  floatx4 acc[2][4];
  #pragma unroll
  for (int mt = 0; mt < 2; mt++)
    #pragma unroll
    for (int nt = 0; nt < 4; nt++)
      acc[mt][nt] = (floatx4){0.f, 0.f, 0.f, 0.f};

  const int f_base = fc * 256;
  for (int step = 0; step < 4; step++) {
    const int f0 = f_base + step * 64;

    // stage A: 128 rows x 64 fp16; 1024 16B-chunks, 4/thread
    #pragma unroll
    for (int j = 0; j < 4; j++) {
      int idx = tid + j * 256;
      int r = idx >> 3, ch = idx & 7;
      uint4 v = *(const uint4*)&pooled[(size_t)(r * N_ + n) * FLAT_ + f0 + ch * 8];
      *(uint4*)&As[r * 72 + ch * 8] = v;
    }
    // stage B: w slice [64 k][64 o]; cvt fp32->fp16 + transpose via half2 packs
    const float* wg = &lin1_w[(size_t)n * (FLAT_ * FD_) + (size_t)f0 * FD_];
    #pragma unroll
    for (int it = 0; it < 2; it++) {
      int p = tid + it * 256;            // 512 (k-pair, o-quad) units
      int o0 = (p & 15) * 4, k0 = (p >> 4) * 2;
      const float* wgk = wg + k0 * 64 + o0;
      float4 va = *(const float4*)wgk;
      float4 vb = *(const float4*)(wgk + 64);
      *(half2v*)&Bt[(o0 + 0) * 72 + k0] = (half2v){(_Float16)va.x, (_Float16)vb.x};
      *(half2v*)&Bt[(o0 + 1) * 72 + k0] = (half2v){(_Float16)va.y, (_Float16)vb.y};
      *(half2v*)&Bt[(o0 + 2) * 72 + k0] = (half2v){(_Float16)va.z, (_Float16)vb.z};
      *(half2v*)&Bt[(o0 + 3) * 72 + k0] = (half2v){(_Float16)va.w, (_Float16)vb.w};
    }
    __syncthreads();

    #pragma unroll
    for (int kh = 0; kh < 2; kh++) {
      half8 af[2], bf[4];
      #pragma unroll
      for (int mt = 0; mt < 2; mt++)
        af[mt] = *(const half8*)&As[(wave * 32 + mt * 16 + lr) * 72 + kh * 32 + q * 8];
      #pragma unroll
      for (int nt = 0; nt < 4; nt++)
        bf[nt] = *(const half8*)&Bt[(nt * 16 + lr) * 72 + kh * 32 + q * 8];
      #pragma unroll
      for (int mt = 0; mt < 2; mt++)
        #pragma unroll
        for (int nt = 0; nt < 4; nt++)
          acc[mt][nt] = __builtin_amdgcn_mfma_f32_16x16x32_f16(
              af[mt], bf[nt], acc[mt][nt], 0, 0, 0);
    }
    __syncthreads();
  }

  // store partials: D layout col=lane&15, row=quad*4+reg
  float* pb = part + (size_t)fc * T_ * FD_;
  #pragma unroll
  for (int mt = 0; mt < 2; mt++) {
    #pragma unroll
    for (int v = 0; v < 4; v++) {
      int r = wave * 32 + mt * 16 + q * 4 + v;
      size_t base = (size_t)(r * N_ + n) * FD_;
      #pragma unroll
      for (int nt = 0; nt < 4; nt++)
        pb[base + nt * 16 + lr] = acc[mt][nt][v];
    }
  }
}

// ---------------------------------------------------------------------------
// K3a: feats = relu(sum of 16 partials + lin1_b). Grid 544x256, float4/thread.
// ---------------------------------------------------------------------------
__global__ __launch_bounds__(256) void feats_kernel(
    const float* __restrict__ part, const float* __restrict__ lin1_b,
    float* __restrict__ feats) {
  int gid = blockIdx.x * 256 + threadIdx.x;      // T*64/4 = 139264 float4
  int t = gid >> 4, f4 = (gid & 15) * 4;
  int n = t % N_;
  float4 s = *(const float4*)&lin1_b[n * FD_ + f4];
  #pragma unroll
  for (int fc = 0; fc < FCH_; fc++) {
    float4 v = *(const float4*)&part[((size_t)fc * T_ + t) * FD_ + f4];
    s.x += v.x; s.y += v.y; s.z += v.z; s.w += v.w;
  }
  s.x = fmaxf(s.x, 0.f); s.y = fmaxf(s.y, 0.f);
  s.z = fmaxf(s.z, 0.f); s.w = fmaxf(s.w, 0.f);
  *(float4*)&feats[(size_t)t * FD_ + f4] = s;
}

// ---------------------------------------------------------------------------
// K3b: GCN aggregation, block = (graph, f-half of 32). 256 blocks x 256 thr.
// Edges + norms staged in LDS; scatter with LDS atomics (conflict-free banks).
// ---------------------------------------------------------------------------
__global__ __launch_bounds__(256) void gcn_agg_kernel(
    const float* __restrict__ feats, const int* __restrict__ edge_index,
    float* __restrict__ agg) {
  const int b  = blockIdx.x >> 1;
  const int fh = blockIdx.x & 1;        // f0 = fh*32
  const int tid = threadIdx.x;

  __shared__ float fS[N_ * 33], aS[N_ * 33];
  __shared__ int   esrcS[EG_], edstS[EG_];
  __shared__ float nrmS[EG_];
  __shared__ int   degS[N_];
  __shared__ float disS[N_];

  if (tid < N_) degS[tid] = 0;
  const int* srcp = edge_index;
  const int* dstp = edge_index + (B_ * EG_);
  const int e0 = b * EG_, nbase = b * N_;
  for (int e = tid; e < EG_; e += 256) {
    esrcS[e] = srcp[e0 + e] - nbase;
    edstS[e] = dstp[e0 + e] - nbase;
  }
  for (int idx = tid; idx < N_ * 32; idx += 256) {
    int i = idx >> 5, f = idx & 31;
    fS[i * 33 + f] = feats[(size_t)(b * N_ + i) * FD_ + fh * 32 + f];
  }
  __syncthreads();
  for (int e = tid; e < EG_; e += 256) atomicAdd(&degS[edstS[e]], 1);
  __syncthreads();
  if (tid < N_) disS[tid] = rsqrtf((float)(degS[tid] + 1));   // +1 self-loop
  __syncthreads();
  for (int e = tid; e < EG_; e += 256)
    nrmS[e] = disS[esrcS[e]] * disS[edstS[e]];
  for (int idx = tid; idx < N_ * 32; idx += 256) {
    int i = idx >> 5, f = idx & 31;
    float d = disS[i];
    aS[i * 33 + f] = d * d * fS[i * 33 + f];
  }
  __syncthreads();
  for (int idx = tid; idx < EG_ * 32; idx += 256) {
    int e = idx >> 5, f = idx & 31;
    atomicAdd(&aS[edstS[e] * 33 + f], nrmS[e] * fS[esrcS[e] * 33 + f]);
  }
  __syncthreads();
  for (int idx = tid; idx < N_ * 32; idx += 256) {
    int i = idx >> 5, f = idx & 31;
    agg[(size_t)(b * N_ + i) * FD_ + fh * 32 + f] = aS[i * 33 + f];
  }
}

// ---------------------------------------------------------------------------
// K3c: per-graph GEMM [68,64]@[64,128] + gcn_b + relu + mean-pool + MLP head.
// 128 blocks x 512 threads; w column hoisted to VGPRs (conflict-free reads).
// ---------------------------------------------------------------------------
__global__ __launch_bounds__(512) void gcn_head_kernel(
    const float* __restrict__ agg, const float* __restrict__ gcn_w,
    const float* __restrict__ gcn_b, const float* __restrict__ w1,
    const float* __restrict__ b1, const float* __restrict__ w2,
    const float* __restrict__ b2, float* __restrict__ out) {
  const int b = blockIdx.x;
  const int tid = threadIdx.x;

  __shared__ float aS[N_ * 68];      // [68][64] pitch 68
  __shared__ float wS[FD_ * GH_];    // 32 KB
  __shared__ float gP[4][GH_];
  __shared__ float z1S[64];

  for (int i4 = tid; i4 < N_ * 16; i4 += 512) {
    int i = i4 >> 4, qf = (i4 & 15) * 4;
    *(float4*)&aS[i * 68 + qf] = *(const float4*)&agg[(size_t)(b * N_ + i) * FD_ + qf];
  }
  #pragma unroll
  for (int j = 0; j < 4; j++)
    ((float4*)wS)[tid + j * 512] = ((const float4*)gcn_w)[tid + j * 512];
  __syncthreads();

  const int j = tid & 127, ig = tid >> 7;
  float wc[64];
  #pragma unroll
  for (int k = 0; k < 64; k++) wc[k] = wS[k * GH_ + j];
  const float bias = gcn_b[j];
  float gsum = 0.f;
  for (int i = ig; i < N_; i += 4) {
    float acc = bias;
    #pragma unroll
    for (int kq = 0; kq < 16; kq++) {
      float4 a = *(const float4*)&aS[i * 68 + kq * 4];   // broadcast
      acc += a.x * wc[kq * 4] + a.y * wc[kq * 4 + 1]
           + a.z * wc[kq * 4 + 2] + a.w * wc[kq * 4 + 3];
    }
    gsum += fmaxf(acc, 0.f);
  }
  gP[ig][j] = gsum;
  __syncthreads();
  if (tid < GH_)
    gP[0][tid] = (gP[0][tid] + gP[1][tid] + gP[2][tid] + gP[3][tid]) * (1.f / 68.f);
  __syncthreads();
  if (tid < 64) {
    float s = b1[tid];
    #pragma unroll 8
    for (int jj = 0; jj < GH_; jj++) s += gP[0][jj] * w1[jj * 64 + tid];
    z1S[tid] = fmaxf(s, 0.f);
  }
  __syncthreads();
  if (tid < 2) {
    float s = b2[tid];
    #pragma unroll 8
    for (int jj = 0; jj < 64; jj++) s += z1S[jj] * w2[jj * 2 + tid];
    out[b * 2 + tid] = s;
  }
}

// ---------------------------------------------------------------------------
extern "C" void kernel_launch(void* const* d_in, const int* in_sizes, int n_in,
                              void* d_out, int out_size, void* d_ws, size_t ws_size,
                              hipStream_t stream) {
  const float* x        = (const float*)d_in[0];
  const int*   edge_idx = (const int*)d_in[1];
  // d_in[2] = batch (layout known: t -> t/N), unused
  const float* conv_w   = (const float*)d_in[3];
  const float* conv_b   = (const float*)d_in[4];
  const float* lin1_w   = (const float*)d_in[5];
  const float* lin1_b   = (const float*)d_in[6];
  const float* gcn_w    = (const float*)d_in[7];
  const float* gcn_b    = (const float*)d_in[8];
  const float* mlp_w1   = (const float*)d_in[9];
  const float* mlp_b1   = (const float*)d_in[10];
  const float* mlp_w2   = (const float*)d_in[11];
  const float* mlp_b2   = (const float*)d_in[12];
  float* outp = (float*)d_out;

  char* wsb = (char*)d_ws;
  _Float16* pooled = (_Float16*)wsb;                               // 71.3 MB
  float* part  = (float*)(wsb + (size_t)T_ * FLAT_ * 2);           // 35.7 MB
  float* feats = part + (size_t)FCH_ * T_ * FD_;                   //  2.2 MB
  float* agg   = feats + (size_t)T_ * FD_;                         //  2.2 MB

  conv_pool_kernel<<<T_, 256, 0, stream>>>(x, conv_w, conv_b, pooled);
  lin1_mfma_kernel<<<N_ * FCH_, 256, 0, stream>>>(pooled, lin1_w, part);
  feats_kernel<<<544, 256, 0, stream>>>(part, lin1_b, feats);
  gcn_agg_kernel<<<B_ * 2, 256, 0, stream>>>(feats, edge_idx, agg);
  gcn_head_kernel<<<B_, 512, 0, stream>>>(agg, gcn_w, gcn_b,
                                          mlp_w1, mlp_b1, mlp_w2, mlp_b2, outp);
}